// Round 5
// baseline (456.592 us; speedup 1.0000x reference)
//
#include <hip/hip_runtime.h>
#include <float.h>
#include <math.h>

// Problem constants
#define D_REAL 2331   // 259 channels * 3*3 patch
#define D_PAD  2336   // bf16 matrix row length
#define DQ     2304   // fp8 matrix row length (resp dims only; 18*128)
#define N_REAL 7225   // 85*85 patches
#define N_PAD  7296   // 57*128
#define JTILES 57
#define ITILES 57
#define STILES 15     // ceil(57/4) supertile grid per dim

typedef __attribute__((ext_vector_type(8))) short bf16x8_t;  // 8 bf16 = 4 VGPRs
typedef __attribute__((ext_vector_type(4))) float f32x4_t;   // 16x16 MFMA C/D
typedef __attribute__((ext_vector_type(8))) int   v8i_t;     // MX A/B operand
typedef __attribute__((ext_vector_type(4))) int   v4i_t;

__device__ __forceinline__ unsigned short f2bf(float x) {
    union { float f; unsigned int u; } v; v.f = x;
    unsigned int r = v.u + 0x7FFFu + ((v.u >> 16) & 1u);   // RNE
    return (unsigned short)(r >> 16);
}
__device__ __forceinline__ float bflo(unsigned int u) {
    union { unsigned int x; float f; } v; v.x = u << 16; return v.f;
}
__device__ __forceinline__ float bfhi(unsigned int u) {
    union { unsigned int x; float f; } v; v.x = u & 0xFFFF0000u; return v.f;
}

#define GLOAD_LDS16(g, l) __builtin_amdgcn_global_load_lds( \
    (const __attribute__((address_space(1))) void*)(g),     \
    (__attribute__((address_space(3))) void*)(l), 16, 0, 0)

// ---------------------------------------------------------------------------
// Fused build: resp part -> bf16 Pb[n][0..2304) AND fp8 Pq[n][0..2304);
// map part -> bf16 Pb[n][2304..2336) only (50 * avgpool4 + zero pad).
__global__ __launch_bounds__(256) void build_all(
        const float* __restrict__ respS, const float* __restrict__ respI,
        const float* __restrict__ mapS,  const float* __restrict__ mapI,
        unsigned short* __restrict__ PbS, unsigned short* __restrict__ PbI,
        unsigned char* __restrict__ PqS, unsigned char* __restrict__ PqI) {
    const int mat = blockIdx.y;
    unsigned short* Pb = mat ? PbI : PbS;
    const int bx = blockIdx.x;
    if (bx < 6120) {
        const float* resp = mat ? respI : respS;
        unsigned char* Pq = mat ? PqI : PqS;
        __shared__ float slab[5 * 768];        // [cc][rr][col], 15 KB max
        const int u  = bx / 72;                // 0..84
        const int d0 = (bx - u * 72) * 32;     // 0..2272
        const int c0 = d0 / 9;
        const int cN = (d0 + 31) / 9 - c0 + 1; // <= 5
        const int total4 = cN * 192;           // float4 count (768/4 per cc)
        for (int idx = threadIdx.x; idx < total4; idx += 256) {
            int cc = idx / 192;
            int rem = idx - cc * 192;          // float4 index within cc
            *(float4*)&slab[cc * 768 + rem * 4] =
                *(const float4*)&resp[(((size_t)(c0 + cc)) << 16)
                                      + ((size_t)(3 * u) << 8) + rem * 4];
        }
        __syncthreads();
        const int dl16 = threadIdx.x & 15;     // d-pair index
        const int de = d0 + 2 * dl16, dq = de + 1;
        const int ce = de / 9, re = de - ce * 9, pe = re / 3, qe = re - pe * 3;
        const int co = dq / 9, ro = dq - co * 9, po = ro / 3, qo = ro - po * 3;
        const int base_e = (ce - c0) * 768 + pe * 256 + qe;
        const int base_o = (co - c0) * 768 + po * 256 + qo;
        const int v0 = threadIdx.x >> 4;       // 0..15
        for (int v = v0; v < 85; v += 16) {
            float x0 = slab[base_e + 3 * v];
            float x1 = slab[base_o + 3 * v];
            size_t row = (size_t)(u * 85 + v);
            *(unsigned int*)&Pb[row * D_PAD + de] =
                (unsigned int)f2bf(x0) | ((unsigned int)f2bf(x1) << 16);
            int pk = __builtin_amdgcn_cvt_pk_fp8_f32(x0, x1, 0, false);
            *(unsigned short*)&Pq[row * DQ + de] = (unsigned short)pk;
        }
    } else {
        const float* map = mat ? mapI : mapS;
        int t = (bx - 6120) * 256 + threadIdx.x;
        int n = t >> 5, dm = t & 31;
        if (n >= N_REAL) return;
        float val = 0.f;
        if (dm < 27) {
            int u = n / 85, v = n - u * 85;
            int ch = dm / 9, r9 = dm - ch * 9, p = r9 / 3, q = r9 - p * 3;
            const float* mp = map + ((size_t)ch << 20)
                                  + ((size_t)((3 * u + p) * 4) << 10)
                                  + (size_t)((3 * v + q) * 4);
            float s = 0.f;
            #pragma unroll
            for (int a = 0; a < 4; a++)
                #pragma unroll
                for (int b = 0; b < 4; b++) s += mp[a * 1024 + b];
            val = 3.125f * s;                  // 50 * (1/16)
        }
        Pb[(size_t)n * D_PAD + 2304 + dm] = f2bf(val);
    }
}

// ---------------------------------------------------------------------------
// sinv[n] = 1/||S[:,n]|| (bf16 matrix).
__global__ __launch_bounds__(256) void col_norms(const unsigned short* __restrict__ Sb,
                                                 float* __restrict__ sinv) {
    int n = blockIdx.x * 4 + (threadIdx.x >> 6);
    int lane = threadIdx.x & 63;
    const uint4* sp = (const uint4*)(Sb + (size_t)n * D_PAD);
    float s = 0.f;
    for (int k = lane; k < D_PAD / 8; k += 64) {
        uint4 a = sp[k];
        float x0 = bflo(a.x), x1 = bfhi(a.x), x2 = bflo(a.y), x3 = bfhi(a.y);
        float x4 = bflo(a.z), x5 = bfhi(a.z), x6 = bflo(a.w), x7 = bfhi(a.w);
        s = fmaf(x0, x0, s); s = fmaf(x1, x1, s);
        s = fmaf(x2, x2, s); s = fmaf(x3, x3, s);
        s = fmaf(x4, x4, s); s = fmaf(x5, x5, s);
        s = fmaf(x6, x6, s); s = fmaf(x7, x7, s);
    }
    #pragma unroll
    for (int off = 32; off > 0; off >>= 1) s += __shfl_xor(s, off);
    if (lane == 0) sinv[n] = (n < N_REAL) ? rsqrtf(s) : 0.f;
}

// ---------------------------------------------------------------------------
// MX-fp8 GEMM + fused argmax (best-measured R0 structure).
// K split: 18 x (16x16x128 f8f6f4, unit scales) over the resp dims + 1 x
// (16x16x32 bf16) tail over the 50x-weighted map dims (same f32 acc).
// Double-buffered 16KB fp8 tiles (64KB LDS, 2 blocks/CU), XOR chunk swizzle,
// 4x4 supertile swizzle. T5 setprio around the MFMA cluster: the two
// independent co-resident blocks provide the wave role-diversity setprio
// needs to arbitrate.
__global__ __launch_bounds__(256) void gemm_argmax(
        const unsigned char* __restrict__ Sq, const unsigned char* __restrict__ Iq,
        const unsigned short* __restrict__ Sb, const unsigned short* __restrict__ Ib,
        const float* __restrict__ sinv,
        float* __restrict__ pval, int* __restrict__ pidx) {
    const int lb = blockIdx.x;
    const int sup = lb >> 4, win = lb & 15;
    const int it4 = (sup / STILES) * 4 + (win & 3);
    const int jt4 = (sup % STILES) * 4 + (win >> 2);
    if (it4 >= ITILES || jt4 >= JTILES) return;   // uniform: no barrier executed
    const int i0 = it4 * 128, j0 = jt4 * 128;

    __shared__ __align__(16) unsigned char Af[2][128][128];   // 32 KB
    __shared__ __align__(16) unsigned char Bf[2][128][128];   // 32 KB
    const int tid = threadIdx.x;
    const int L = tid & 63, w = tid >> 6;
    const int m = L & 15, q = L >> 4;
    const int wi = (w >> 1) * 64, wj = (w & 1) * 64;

    f32x4_t acc[4][4];
    #pragma unroll
    for (int a = 0; a < 4; a++)
        #pragma unroll
        for (int b = 0; b < 4; b++) acc[a][b] = (f32x4_t){0.f, 0.f, 0.f, 0.f};

    // fp8 staging: lane L -> LDS row rl = L>>3 (128B rows), chunk pos L&7;
    // global 16B chunk ck = (L&7) ^ (rl&7)  (XOR involution, spreads banks).
    const int rl = L >> 3;
    const int ck = (L & 7) ^ rl;
    const unsigned char* gqa = Sq + (size_t)(i0 + w * 32 + rl) * DQ + (ck << 4);
    const unsigned char* gqb = Iq + (size_t)(j0 + w * 32 + rl) * DQ + (ck << 4);

    // read-side swizzled 16B-chunk byte offsets (row r: stored = c ^ (r&7); r&7 == m&7)
    const int clo = ((((q << 1))     ^ (m & 7)) << 4);
    const int chi = ((((q << 1) | 1) ^ (m & 7)) << 4);

    // bf16 tail staging, overlaid on buffer-0 regions (8KB each)
    unsigned short (*At)[32] = (unsigned short(*)[32])&Af[0][0][0];
    unsigned short (*Bt)[32] = (unsigned short(*)[32])&Bf[0][0][0];
    const int rl2 = L >> 2;
    const int ck2 = (L & 3) ^ ((rl2 >> 1) & 3);
    const unsigned short* gta = Sb + (size_t)(i0 + w * 32 + rl2) * D_PAD + 2304 + (ck2 << 3);
    const unsigned short* gtb = Ib + (size_t)(j0 + w * 32 + rl2) * D_PAD + 2304 + (ck2 << 3);
    const int cht = (q ^ ((m >> 1) & 3)) << 3;   // tail read chunk (shorts)

#define PREFETCH_Q(buf) {                                     \
    GLOAD_LDS16(gqa,             &Af[buf][w * 32     ][0]);   \
    GLOAD_LDS16(gqa +  8 * DQ,   &Af[buf][w * 32 +  8][0]);   \
    GLOAD_LDS16(gqa + 16 * DQ,   &Af[buf][w * 32 + 16][0]);   \
    GLOAD_LDS16(gqa + 24 * DQ,   &Af[buf][w * 32 + 24][0]);   \
    GLOAD_LDS16(gqb,             &Bf[buf][w * 32     ][0]);   \
    GLOAD_LDS16(gqb +  8 * DQ,   &Bf[buf][w * 32 +  8][0]);   \
    GLOAD_LDS16(gqb + 16 * DQ,   &Bf[buf][w * 32 + 16][0]);   \
    GLOAD_LDS16(gqb + 24 * DQ,   &Bf[buf][w * 32 + 24][0]);   \
    gqa += 128; gqb += 128; }

#define COMPUTE_Q(buf) {                                                   \
    v8i_t aq[4], bq[4];                                                    \
    _Pragma("unroll")                                                      \
    for (int mi = 0; mi < 4; mi++) {                                       \
        v4i_t lo = *(const v4i_t*)&Af[buf][wi + mi * 16 + m][clo];         \
        v4i_t hi = *(const v4i_t*)&Af[buf][wi + mi * 16 + m][chi];         \
        aq[mi] = __builtin_shufflevector(lo, hi, 0, 1, 2, 3, 4, 5, 6, 7);  \
    }                                                                      \
    _Pragma("unroll")                                                      \
    for (int nj = 0; nj < 4; nj++) {                                       \
        v4i_t lo = *(const v4i_t*)&Bf[buf][wj + nj * 16 + m][clo];         \
        v4i_t hi = *(const v4i_t*)&Bf[buf][wj + nj * 16 + m][chi];         \
        bq[nj] = __builtin_shufflevector(lo, hi, 0, 1, 2, 3, 4, 5, 6, 7);  \
    }                                                                      \
    __builtin_amdgcn_s_setprio(1);                                         \
    _Pragma("unroll")                                                      \
    for (int mi = 0; mi < 4; mi++)                                         \
        _Pragma("unroll")                                                  \
        for (int nj = 0; nj < 4; nj++)                                     \
            acc[mi][nj] = __builtin_amdgcn_mfma_scale_f32_16x16x128_f8f6f4(\
                aq[mi], bq[nj], acc[mi][nj], 0, 0, 0, 0x7F, 0, 0x7F);      \
    __builtin_amdgcn_s_setprio(0); }

    PREFETCH_Q(0)                              // fp8 tile 0 -> buf 0
    for (int p = 0; p < 8; p++) {              // fp8 tiles 0..15
        __syncthreads();
        PREFETCH_Q(1)
        __builtin_amdgcn_sched_barrier(0);
        COMPUTE_Q(0)
        __syncthreads();
        PREFETCH_Q(0)
        __builtin_amdgcn_sched_barrier(0);
        COMPUTE_Q(1)
    }
    __syncthreads();
    PREFETCH_Q(1)                              // fp8 tile 17
    __builtin_amdgcn_sched_barrier(0);
    COMPUTE_Q(0)                               // fp8 tile 16
    __syncthreads();
    {                                          // bf16 map-dim tail -> buf0 overlay
        GLOAD_LDS16(gta,                      &At[w * 32][0]);
        GLOAD_LDS16(gta + (size_t)16 * D_PAD, &At[w * 32 + 16][0]);
        GLOAD_LDS16(gtb,                      &Bt[w * 32][0]);
        GLOAD_LDS16(gtb + (size_t)16 * D_PAD, &Bt[w * 32 + 16][0]);
    }
    __builtin_amdgcn_sched_barrier(0);
    COMPUTE_Q(1)                               // fp8 tile 17
    __syncthreads();                           // tail tiles ready
    {
        bf16x8_t af[4], bfr[4];
        #pragma unroll
        for (int mi = 0; mi < 4; mi++)
            af[mi] = *(const bf16x8_t*)&At[wi + mi * 16 + m][cht];
        #pragma unroll
        for (int nj = 0; nj < 4; nj++)
            bfr[nj] = *(const bf16x8_t*)&Bt[wj + nj * 16 + m][cht];
        #pragma unroll
        for (int mi = 0; mi < 4; mi++)
            #pragma unroll
            for (int nj = 0; nj < 4; nj++)
                acc[mi][nj] = __builtin_amdgcn_mfma_f32_16x16x32_bf16(
                    af[mi], bfr[nj], acc[mi][nj], 0, 0, 0);
    }
#undef PREFETCH_Q
#undef COMPUTE_Q

    // Epilogue. C/D layout: col = m (j-dir), row = q*4 + reg (i-dir).
    float sjv[4];
    #pragma unroll
    for (int nj = 0; nj < 4; nj++) sjv[nj] = sinv[j0 + wj + nj * 16 + m];
    #pragma unroll
    for (int mi = 0; mi < 4; mi++) {
        #pragma unroll
        for (int r = 0; r < 4; r++) {
            float best = -INFINITY; int bidx = 0x7fffffff;
            #pragma unroll
            for (int nj = 0; nj < 4; nj++) {   // j ascending -> '>' keeps smallest
                int j = j0 + wj + nj * 16 + m;
                float v = (j < N_REAL) ? acc[mi][nj][r] * sjv[nj] : -INFINITY;
                if (v > best) { best = v; bidx = j; }
            }
            #pragma unroll
            for (int off = 1; off < 16; off <<= 1) {
                float ov = __shfl_xor(best, off);
                int   oi = __shfl_xor(bidx, off);
                if (ov > best || (ov == best && oi < bidx)) { best = ov; bidx = oi; }
            }
            if (m == 0) {
                int i = i0 + wi + mi * 16 + q * 4 + r;
                pval[(size_t)jt4 * N_PAD + i] = best;
                pidx[(size_t)jt4 * N_PAD + i] = bidx;
            }
        }
    }
}

// ---------------------------------------------------------------------------
// Merge the 57 per-jtile argmax partials -> jbest[n]. Fully coalesced across
// n; removes the serial wave-0 merge phase from every loss block.
__global__ __launch_bounds__(256) void merge_argmax(
        const float* __restrict__ pval, const int* __restrict__ pidx,
        int* __restrict__ jbest) {
    int n = blockIdx.x * 256 + threadIdx.x;
    if (n >= N_REAL) return;
    float best = pval[n];
    int   id   = pidx[n];
    #pragma unroll 4
    for (int jt = 1; jt < JTILES; jt++) {
        float v  = pval[(size_t)jt * N_PAD + n];
        int   oi = pidx[(size_t)jt * N_PAD + n];
        if (v > best || (v == best && oi < id)) { best = v; id = oi; }
    }
    jbest[n] = id;
}

// ---------------------------------------------------------------------------
// Loss: pure 2-row read + reduce per block (no serial prologue).
__global__ __launch_bounds__(256) void loss_kernel(
        const unsigned short* __restrict__ Ib, const unsigned short* __restrict__ Sb,
        const int* __restrict__ jbest, double* __restrict__ partial) {
    __shared__ float wsum[4];
    const int n = blockIdx.x;
    const int jn = jbest[n];
    const uint4* ip = (const uint4*)(Ib + (size_t)n  * D_PAD);
    const uint4* sp = (const uint4*)(Sb + (size_t)jn * D_PAD);
    float s = 0.f;
    for (int k = threadIdx.x; k < D_PAD / 8; k += 256) {
        uint4 a = ip[k], b = sp[k];
        float d0 = bflo(a.x) - bflo(b.x), d1 = bfhi(a.x) - bfhi(b.x);
        float d2 = bflo(a.y) - bflo(b.y), d3 = bfhi(a.y) - bfhi(b.y);
        float d4 = bflo(a.z) - bflo(b.z), d5 = bfhi(a.z) - bfhi(b.z);
        float d6 = bflo(a.w) - bflo(b.w), d7 = bfhi(a.w) - bfhi(b.w);
        s = fmaf(d0, d0, s); s = fmaf(d1, d1, s);
        s = fmaf(d2, d2, s); s = fmaf(d3, d3, s);
        s = fmaf(d4, d4, s); s = fmaf(d5, d5, s);
        s = fmaf(d6, d6, s); s = fmaf(d7, d7, s);
    }
    #pragma unroll
    for (int off = 32; off > 0; off >>= 1) s += __shfl_xor(s, off);
    int lane = threadIdx.x & 63, wv = threadIdx.x >> 6;
    if (lane == 0) wsum[wv] = s;
    __syncthreads();
    if (threadIdx.x == 0) {
        partial[n] = (double)wsum[0] + (double)wsum[1]
                   + (double)wsum[2] + (double)wsum[3];
    }
}

// One-block tree reduction of the 7225 per-row partials.
__global__ __launch_bounds__(256) void finalize(const double* __restrict__ partial,
                                                float* __restrict__ out) {
    __shared__ double ws[4];
    double s = 0.0;
    for (int i = threadIdx.x; i < N_REAL; i += 256) s += partial[i];
    #pragma unroll
    for (int off = 32; off > 0; off >>= 1) s += __shfl_xor(s, off);
    int lane = threadIdx.x & 63, wv = threadIdx.x >> 6;
    if (lane == 0) ws[wv] = s;
    __syncthreads();
    if (threadIdx.x == 0) {
        double t = ws[0] + ws[1] + ws[2] + ws[3];
        out[0] = (float)(t / (double)((long long)D_REAL * N_REAL));
    }
}

// ---------------------------------------------------------------------------
extern "C" void kernel_launch(void* const* d_in, const int* in_sizes, int n_in,
                              void* d_out, int out_size, void* d_ws, size_t ws_size,
                              hipStream_t stream) {
    const float* style_resp = (const float*)d_in[0];
    const float* style_map  = (const float*)d_in[1];
    const float* output_map = (const float*)d_in[2];
    const float* model_resp = (const float*)d_in[3];
    float* out = (float*)d_out;

    unsigned short* Sb = (unsigned short*)d_ws;
    unsigned short* Ib = Sb + (size_t)D_PAD * N_PAD;
    unsigned char*  Sq = (unsigned char*)(Ib + (size_t)D_PAD * N_PAD);
    unsigned char*  Iq = Sq + (size_t)DQ * N_PAD;
    float* sinv     = (float*)(Iq + (size_t)DQ * N_PAD);
    float* pval     = sinv + N_PAD;
    int*   pidx     = (int*)(pval + (size_t)JTILES * N_PAD);
    double* partial = (double*)(pidx + (size_t)JTILES * N_PAD);
    int*   jbest    = (int*)(partial + N_PAD);

    // resp tiles: 85*72 = 6120 blocks; map part: ceil(7225*32/256) = 904 blocks
    build_all<<<dim3(6120 + 904, 2), 256, 0, stream>>>(
        style_resp, model_resp, style_map, output_map, Sb, Ib, Sq, Iq);

    col_norms<<<N_PAD / 4, 256, 0, stream>>>(Sb, sinv);

    gemm_argmax<<<STILES * STILES * 16, 256, 0, stream>>>(Sq, Iq, Sb, Ib, sinv, pval, pidx);

    merge_argmax<<<(N_REAL + 255) / 256, 256, 0, stream>>>(pval, pidx, jbest);

    loss_kernel<<<N_REAL, 256, 0, stream>>>(Ib, Sb, jbest, partial);
    finalize<<<1, 256, 0, stream>>>(partial, out);
}